// Round 3
// baseline (24740.843 us; speedup 1.0000x reference)
//
#include <hip/hip_runtime.h>
#include <hip/hip_bf16.h>

// TGCN: B=64, T=500, N=21, HID=128.
// One block per batch element (64 x 704 threads), full T-loop in-kernel,
// H1/H2 in LDS. Round 3: column-blocking F=2 — thread (g,f0) owns rows
// {2g,2g+1} (row 21 zero-padded) and columns {f0,f0+64}; halves the
// CU-shared LDS-pipe traffic (the round-1 bottleneck) while keeping every
// weight load coalesced. Per-element accumulation order is IDENTICAL to
// the passing round-1 kernel (scalar fmaf chains, same chunk order) — do
// NOT reorder sums inside the recurrence; the 1.33e-6 threshold is thin.

#define NN 21
#define NROW 22            // padded rows in LDS state arrays
#define HID 128
#define TSTEPS 500
#define EDGES 210
#define NTHREADS 704       // 11 waves

// ws layout (float offsets)
#define WS_A     0        // 441 floats
#define WS_VEC   448      // 9*128
#define WS_LZR1  1600     // 32*256*4
#define WS_LH1   34368    // 32*128*4
#define WS_WE2   50752    // 32*384*4
#define WS_LZR2  99904    // 32*256*4
#define WS_LH2   132672   // 32*128*4

__device__ __forceinline__ float fma4(float4 a, float4 b, float acc) {
    acc = fmaf(a.x, b.x, acc);
    acc = fmaf(a.y, b.y, acc);
    acc = fmaf(a.z, b.z, acc);
    acc = fmaf(a.w, b.w, acc);
    return acc;
}

__device__ __forceinline__ float sigmoidf(float v) {
    return 1.0f / (1.0f + expf(-v));
}

// ---- Prologue: build normalized adjacency A (21x21) in fp64, store fp32 ----
__global__ void build_A(const int* __restrict__ ei, const float* __restrict__ ew,
                        float* __restrict__ Aout) {
    __shared__ double deg[NN];
    __shared__ double dinv[NN];
    __shared__ double Asm[NN * NN];
    int t = threadIdx.x;
    for (int k = t; k < NN * NN; k += blockDim.x) Asm[k] = 0.0;
    if (t < NN) deg[t] = 1.0;  // self loop weight 1
    __syncthreads();
    if (t == 0) {
        for (int e = 0; e < EDGES; e++) deg[ei[EDGES + e]] += (double)ew[e];
        for (int i = 0; i < NN; i++) dinv[i] = deg[i] > 0.0 ? 1.0 / sqrt(deg[i]) : 0.0;
        for (int e = 0; e < EDGES; e++) {
            int s = ei[e], d = ei[EDGES + e];
            Asm[d * NN + s] += dinv[s] * (double)ew[e] * dinv[d];
        }
        for (int i = 0; i < NN; i++) Asm[i * NN + i] += dinv[i] * dinv[i];
    }
    __syncthreads();
    for (int k = t; k < NN * NN; k += blockDim.x) Aout[k] = (float)Asm[k];
}

// ---- Prologue: repack bottom halves of (256,128) concat weights ----
__global__ void pack_bot(const float* __restrict__ w0, const float* __restrict__ w1,
                         float4* __restrict__ out, int ngate) {
    int t = blockIdx.x * blockDim.x + threadIdx.x;
    int ncol = ngate * 128;
    int total = 32 * ncol;
    if (t >= total) return;
    int c = t / ncol, col = t - c * ncol;
    const float* src = (col < 128) ? w0 : w1;
    int f = col & 127;
    int k = 4 * c;
    float4 v;
    v.x = src[(128 + k + 0) * 128 + f];
    v.y = src[(128 + k + 1) * 128 + f];
    v.z = src[(128 + k + 2) * 128 + f];
    v.w = src[(128 + k + 3) * 128 + f];
    out[t] = v;
}

// ---- Prologue: Weff2_g = Wg_2 @ lgw_2_top, packed [c][g*128+f], fp64 accum ----
__global__ void make_weff2(const float* __restrict__ Wz2, const float* __restrict__ Wr2,
                           const float* __restrict__ Wh2,
                           const float* __restrict__ lzw2, const float* __restrict__ lrw2,
                           const float* __restrict__ lhw2,
                           float4* __restrict__ out) {
    int t = blockIdx.x * blockDim.x + threadIdx.x;  // [0, 32*384)
    if (t >= 32 * 384) return;
    int c = t / 384, col = t - c * 384;
    int g = col >> 7, f = col & 127;
    const float* W = (g == 0) ? Wz2 : (g == 1) ? Wr2 : Wh2;
    const float* L = (g == 0) ? lzw2 : (g == 1) ? lrw2 : lhw2;
    double a0 = 0, a1 = 0, a2 = 0, a3 = 0;
    for (int m = 0; m < 128; m++) {
        double lm = (double)L[m * 128 + f];
        a0 += (double)W[(4 * c + 0) * 128 + m] * lm;
        a1 += (double)W[(4 * c + 1) * 128 + m] * lm;
        a2 += (double)W[(4 * c + 2) * 128 + m] * lm;
        a3 += (double)W[(4 * c + 3) * 128 + m] * lm;
    }
    out[t] = make_float4((float)a0, (float)a1, (float)a2, (float)a3);
}

// ---- Prologue: layer-1 effective row vectors + all bias consts (fp64) ----
__global__ void make_vecs(const float* __restrict__ Wz1, const float* __restrict__ Wr1,
                          const float* __restrict__ Wh1,
                          const float* __restrict__ bz1, const float* __restrict__ br1,
                          const float* __restrict__ bh1,
                          const float* __restrict__ lzw1, const float* __restrict__ lrw1,
                          const float* __restrict__ lhw1,
                          const float* __restrict__ lzb1, const float* __restrict__ lrb1,
                          const float* __restrict__ lhb1,
                          const float* __restrict__ bz2, const float* __restrict__ br2,
                          const float* __restrict__ bh2,
                          const float* __restrict__ lzw2, const float* __restrict__ lrw2,
                          const float* __restrict__ lhw2,
                          const float* __restrict__ lzb2, const float* __restrict__ lrb2,
                          const float* __restrict__ lhb2,
                          float* __restrict__ out) {
    int t = blockIdx.x * blockDim.x + threadIdx.x;
    if (t >= 9 * 128) return;
    int v = t >> 7, f = t & 127;
    double acc = 0.0;
    if (v < 3) {
        const float* W = (v == 0) ? Wz1 : (v == 1) ? Wr1 : Wh1;   // (1,128)
        const float* L = (v == 0) ? lzw1 : (v == 1) ? lrw1 : lhw1;
        for (int m = 0; m < 128; m++) acc += (double)W[m] * (double)L[m * 128 + f];
    } else if (v < 6) {
        int g = v - 3;
        const float* bb = (g == 0) ? bz1 : (g == 1) ? br1 : bh1;
        const float* L  = (g == 0) ? lzw1 : (g == 1) ? lrw1 : lhw1;
        const float* lb = (g == 0) ? lzb1 : (g == 1) ? lrb1 : lhb1;
        for (int m = 0; m < 128; m++) acc += (double)bb[m] * (double)L[m * 128 + f];
        acc += (double)lb[f];
    } else {
        int g = v - 6;
        const float* bb = (g == 0) ? bz2 : (g == 1) ? br2 : bh2;
        const float* L  = (g == 0) ? lzw2 : (g == 1) ? lrw2 : lhw2;
        const float* lb = (g == 0) ? lzb2 : (g == 1) ? lrb2 : lhb2;
        for (int m = 0; m < 128; m++) acc += (double)bb[m] * (double)L[m * 128 + f];
        acc += (double)lb[f];
    }
    out[t] = (float)acc;
}

// ---- Main: one block per batch element, T=500 steps in-kernel ----
__global__ __launch_bounds__(NTHREADS) void tgcn_main(
    const float* __restrict__ x,       // (64,500,21)
    const float* __restrict__ ws,
    const float* __restrict__ cls_w,   // (128,1)
    const float* __restrict__ cls_b,   // (1,)
    float* __restrict__ out)           // (64,)
{
    const int b  = blockIdx.x;
    const int t  = threadIdx.x;
    const int f0 = t & 63;
    const int f1 = f0 + 64;
    const int g  = __builtin_amdgcn_readfirstlane(t >> 6);  // wave-uniform 0..10
    const int iA = 2 * g, iB = 2 * g + 1;                   // iB==21 is the pad row
    const bool rowB = (iB < NN);                            // wave-uniform

    __shared__ __align__(16) float sH1[NROW * HID];
    __shared__ __align__(16) float sH2[NROW * HID];
    __shared__ __align__(16) float sHR[NROW * HID];
    __shared__ __align__(16) float sAH[NROW * HID];
    __shared__ float sA[NROW * NN];    // 22 rows x 21 cols; row 21 zeroed
    __shared__ float sax[2][NROW];
    __shared__ double sred[11][HID];

    const float*  vecs = ws + WS_VEC;
    const float4* Lzr1 = (const float4*)(ws + WS_LZR1);
    const float4* Lh1  = (const float4*)(ws + WS_LH1);
    const float4* We2  = (const float4*)(ws + WS_WE2);
    const float4* Lzr2 = (const float4*)(ws + WS_LZR2);
    const float4* Lh2  = (const float4*)(ws + WS_LH2);

    const float4* H1v = (const float4*)sH1;   // row stride 32 float4
    const float4* H2v = (const float4*)sH2;
    const float4* HRv = (const float4*)sHR;
    const float4* AHv = (const float4*)sAH;

    for (int k = t; k < NROW * HID; k += NTHREADS) { sH1[k] = 0.0f; sH2[k] = 0.0f; }
    for (int k = t; k < NN * NN; k += NTHREADS) sA[k] = ws[WS_A + k];
    if (t < NN) sA[NN * NN + t] = 0.0f;  // pad row 21 of A

    // per-column constants for both owned columns
    const float wz1a = vecs[f0],        wz1b = vecs[f1];
    const float wr1a = vecs[128 + f0],  wr1b = vecs[128 + f1];
    const float wh1a = vecs[256 + f0],  wh1b = vecs[256 + f1];
    const float cz1a = vecs[384 + f0],  cz1b = vecs[384 + f1];
    const float cr1a = vecs[512 + f0],  cr1b = vecs[512 + f1];
    const float ch1a = vecs[640 + f0],  ch1b = vecs[640 + f1];
    const float cz2a = vecs[768 + f0],  cz2b = vecs[768 + f1];
    const float cr2a = vecs[896 + f0],  cr2b = vecs[896 + f1];
    const float ch2a = vecs[1024 + f0], ch2b = vecs[1024 + f1];

    __syncthreads();

    const float* xb = x + (size_t)b * (TSTEPS * NN);
    if (t < NROW) {  // sax for step 0 (pad row -> 0 since A row 21 is zero)
        float a = 0.0f;
        for (int j = 0; j < NN; j++) a = fmaf(sA[t * NN + j], xb[j], a);
        sax[0][t] = a;
    }
    __syncthreads();

    double oacc0 = 0.0, oacc1 = 0.0;   // per-column time/node partial sums

    for (int step = 0; step < TSTEPS; step++) {
        const int pb = step & 1;
        const float axA = sax[pb][iA], axB = sax[pb][iB];

        // ---------- P1: layer-1 z,r gates ----------
        float azA0 = fmaf(axA, wz1a, cz1a), azA1 = fmaf(axA, wz1b, cz1b);
        float azB0 = fmaf(axB, wz1a, cz1a), azB1 = fmaf(axB, wz1b, cz1b);
        float arA0 = fmaf(axA, wr1a, cr1a), arA1 = fmaf(axA, wr1b, cr1b);
        float arB0 = fmaf(axB, wr1a, cr1a), arB1 = fmaf(axB, wr1b, cr1b);
        #pragma unroll 4
        for (int c = 0; c < 32; ++c) {
            const float4 wz0 = Lzr1[c * 256 + f0];
            const float4 wz1 = Lzr1[c * 256 + f1];
            const float4 wr0 = Lzr1[c * 256 + 128 + f0];
            const float4 wr1 = Lzr1[c * 256 + 128 + f1];
            const float4 hA = H1v[iA * 32 + c];
            const float4 hB = H1v[iB * 32 + c];
            azA0 = fma4(hA, wz0, azA0); azA1 = fma4(hA, wz1, azA1);
            azB0 = fma4(hB, wz0, azB0); azB1 = fma4(hB, wz1, azB1);
            arA0 = fma4(hA, wr0, arA0); arA1 = fma4(hA, wr1, arA1);
            arB0 = fma4(hB, wr0, arB0); arB1 = fma4(hB, wr1, arB1);
        }
        const float zA0 = sigmoidf(azA0), zA1 = sigmoidf(azA1);
        const float zB0 = sigmoidf(azB0), zB1 = sigmoidf(azB1);
        const float rA0 = sigmoidf(arA0), rA1 = sigmoidf(arA1);
        const float rB0 = sigmoidf(arB0), rB1 = sigmoidf(arB1);
        const float h1A0 = sH1[iA * HID + f0], h1A1 = sH1[iA * HID + f1];
        const float h1B0 = sH1[iB * HID + f0], h1B1 = sH1[iB * HID + f1];
        sHR[iA * HID + f0] = h1A0 * rA0;
        sHR[iA * HID + f1] = h1A1 * rA1;
        sHR[iB * HID + f0] = h1B0 * rB0;
        sHR[iB * HID + f1] = h1B1 * rB1;
        __syncthreads();

        // ---------- P2: layer-1 h gate + H1 update ----------
        float ahA0 = fmaf(axA, wh1a, ch1a), ahA1 = fmaf(axA, wh1b, ch1b);
        float ahB0 = fmaf(axB, wh1a, ch1a), ahB1 = fmaf(axB, wh1b, ch1b);
        #pragma unroll 4
        for (int c = 0; c < 32; ++c) {
            const float4 wh0 = Lh1[c * 128 + f0];
            const float4 wh1 = Lh1[c * 128 + f1];
            const float4 qA = HRv[iA * 32 + c];
            const float4 qB = HRv[iB * 32 + c];
            ahA0 = fma4(qA, wh0, ahA0); ahA1 = fma4(qA, wh1, ahA1);
            ahB0 = fma4(qB, wh0, ahB0); ahB1 = fma4(qB, wh1, ahB1);
        }
        const float nA0 = fmaf(zA0, h1A0, (1.0f - zA0) * tanhf(ahA0));
        const float nA1 = fmaf(zA1, h1A1, (1.0f - zA1) * tanhf(ahA1));
        const float nB0 = fmaf(zB0, h1B0, (1.0f - zB0) * tanhf(ahB0));
        const float nB1 = fmaf(zB1, h1B1, (1.0f - zB1) * tanhf(ahB1));
        sH1[iA * HID + f0] = nA0;
        sH1[iA * HID + f1] = nA1;
        sH1[iB * HID + f0] = nB0;
        sH1[iB * HID + f1] = nB1;
        __syncthreads();

        // ---------- P3: AH1 = A @ H1 ----------
        float aaA0 = 0.0f, aaA1 = 0.0f, aaB0 = 0.0f, aaB1 = 0.0f;
        #pragma unroll
        for (int j = 0; j < NN; j++) {
            const float hj0 = sH1[j * HID + f0];
            const float hj1 = sH1[j * HID + f1];
            const float aAj = sA[iA * NN + j];
            const float aBj = sA[iB * NN + j];
            aaA0 = fmaf(aAj, hj0, aaA0);
            aaA1 = fmaf(aAj, hj1, aaA1);
            aaB0 = fmaf(aBj, hj0, aaB0);
            aaB1 = fmaf(aBj, hj1, aaB1);
        }
        sAH[iA * HID + f0] = aaA0;
        sAH[iA * HID + f1] = aaA1;
        sAH[iB * HID + f0] = aaB0;
        sAH[iB * HID + f1] = aaB1;
        __syncthreads();

        // ---------- P4: layer-2 gcn (all gates) + z,r gates ----------
        float pzA0 = cz2a, pzA1 = cz2b, pzB0 = cz2a, pzB1 = cz2b;
        float prA0 = cr2a, prA1 = cr2b, prB0 = cr2a, prB1 = cr2b;
        float phA0 = ch2a, phA1 = ch2b, phB0 = ch2a, phB1 = ch2b;
        #pragma unroll 2
        for (int c = 0; c < 32; ++c) {
            const float4 wz0 = We2[c * 384 + f0];
            const float4 wz1 = We2[c * 384 + f1];
            const float4 wr0 = We2[c * 384 + 128 + f0];
            const float4 wr1 = We2[c * 384 + 128 + f1];
            const float4 wh0 = We2[c * 384 + 256 + f0];
            const float4 wh1 = We2[c * 384 + 256 + f1];
            const float4 lz0 = Lzr2[c * 256 + f0];
            const float4 lz1 = Lzr2[c * 256 + f1];
            const float4 lr0 = Lzr2[c * 256 + 128 + f0];
            const float4 lr1 = Lzr2[c * 256 + 128 + f1];
            const float4 aA = AHv[iA * 32 + c];
            const float4 aB = AHv[iB * 32 + c];
            const float4 gA = H2v[iA * 32 + c];
            const float4 gB = H2v[iB * 32 + c];
            // per-element order: a-chunk then g-chunk per c (matches round 1)
            pzA0 = fma4(aA, wz0, pzA0); pzA0 = fma4(gA, lz0, pzA0);
            pzA1 = fma4(aA, wz1, pzA1); pzA1 = fma4(gA, lz1, pzA1);
            pzB0 = fma4(aB, wz0, pzB0); pzB0 = fma4(gB, lz0, pzB0);
            pzB1 = fma4(aB, wz1, pzB1); pzB1 = fma4(gB, lz1, pzB1);
            prA0 = fma4(aA, wr0, prA0); prA0 = fma4(gA, lr0, prA0);
            prA1 = fma4(aA, wr1, prA1); prA1 = fma4(gA, lr1, prA1);
            prB0 = fma4(aB, wr0, prB0); prB0 = fma4(gB, lr0, prB0);
            prB1 = fma4(aB, wr1, prB1); prB1 = fma4(gB, lr1, prB1);
            phA0 = fma4(aA, wh0, phA0); phA1 = fma4(aA, wh1, phA1);
            phB0 = fma4(aB, wh0, phB0); phB1 = fma4(aB, wh1, phB1);
        }
        const float z2A0 = sigmoidf(pzA0), z2A1 = sigmoidf(pzA1);
        const float z2B0 = sigmoidf(pzB0), z2B1 = sigmoidf(pzB1);
        const float r2A0 = sigmoidf(prA0), r2A1 = sigmoidf(prA1);
        const float r2B0 = sigmoidf(prB0), r2B1 = sigmoidf(prB1);
        const float h2A0 = sH2[iA * HID + f0], h2A1 = sH2[iA * HID + f1];
        const float h2B0 = sH2[iB * HID + f0], h2B1 = sH2[iB * HID + f1];
        sHR[iA * HID + f0] = h2A0 * r2A0;
        sHR[iA * HID + f1] = h2A1 * r2A1;
        sHR[iB * HID + f0] = h2B0 * r2B0;
        sHR[iB * HID + f1] = h2B1 * r2B1;
        __syncthreads();

        // ---------- P5: layer-2 h gate + H2 update + output accum ----------
        #pragma unroll 4
        for (int c = 0; c < 32; ++c) {
            const float4 lh0 = Lh2[c * 128 + f0];
            const float4 lh1 = Lh2[c * 128 + f1];
            const float4 qA = HRv[iA * 32 + c];
            const float4 qB = HRv[iB * 32 + c];
            phA0 = fma4(qA, lh0, phA0); phA1 = fma4(qA, lh1, phA1);
            phB0 = fma4(qB, lh0, phB0); phB1 = fma4(qB, lh1, phB1);
        }
        const float mA0 = fmaf(z2A0, h2A0, (1.0f - z2A0) * tanhf(phA0));
        const float mA1 = fmaf(z2A1, h2A1, (1.0f - z2A1) * tanhf(phA1));
        const float mB0 = fmaf(z2B0, h2B0, (1.0f - z2B0) * tanhf(phB0));
        const float mB1 = fmaf(z2B1, h2B1, (1.0f - z2B1) * tanhf(phB1));
        sH2[iA * HID + f0] = mA0;
        sH2[iA * HID + f1] = mA1;
        sH2[iB * HID + f0] = mB0;
        sH2[iB * HID + f1] = mB1;
        oacc0 += (double)mA0;
        oacc1 += (double)mA1;
        if (rowB) {                 // wave-uniform: exclude pad row 21
            oacc0 += (double)mB0;
            oacc1 += (double)mB1;
        }

        // prefetch next step's ax (threads 0..21; pad row -> 0)
        if (step + 1 < TSTEPS && t < NROW) {
            const float* xt = xb + (step + 1) * NN;
            float a = 0.0f;
            for (int j = 0; j < NN; j++) a = fmaf(sA[t * NN + j], xt[j], a);
            sax[(step + 1) & 1][t] = a;
        }
        __syncthreads();
    }

    // ---------- Epilogue: mean over (T, nodes), dot with cls_w ----------
    sred[g][f0] = oacc0;
    sred[g][f1] = oacc1;
    __syncthreads();
    if (t < HID) {
        double s = 0.0;
        for (int gg = 0; gg < 11; gg++) s += sred[gg][t];
        sred[0][t] = (s / (double)(TSTEPS * NN)) * (double)cls_w[t];
    }
    __syncthreads();
    if (t < 64) {
        double v = ((double*)sred)[t] + ((double*)sred)[t + 64];
        for (int off = 32; off; off >>= 1) v += __shfl_down(v, off, 64);
        if (t == 0) out[b] = (float)(v + (double)cls_b[0]);
    }
}

extern "C" void kernel_launch(void* const* d_in, const int* in_sizes, int n_in,
                              void* d_out, int out_size, void* d_ws, size_t ws_size,
                              hipStream_t stream) {
    const float* x    = (const float*)d_in[0];
    const int*   ei   = (const int*)  d_in[1];
    const float* ew   = (const float*)d_in[2];
    const float* Wz1  = (const float*)d_in[3];
    const float* bz1  = (const float*)d_in[4];
    const float* lzw1 = (const float*)d_in[5];
    const float* lzb1 = (const float*)d_in[6];
    const float* Wr1  = (const float*)d_in[7];
    const float* br1  = (const float*)d_in[8];
    const float* lrw1 = (const float*)d_in[9];
    const float* lrb1 = (const float*)d_in[10];
    const float* Wh1  = (const float*)d_in[11];
    const float* bh1  = (const float*)d_in[12];
    const float* lhw1 = (const float*)d_in[13];
    const float* lhb1 = (const float*)d_in[14];
    const float* Wz2  = (const float*)d_in[15];
    const float* bz2  = (const float*)d_in[16];
    const float* lzw2 = (const float*)d_in[17];
    const float* lzb2 = (const float*)d_in[18];
    const float* Wr2  = (const float*)d_in[19];
    const float* br2  = (const float*)d_in[20];
    const float* lrw2 = (const float*)d_in[21];
    const float* lrb2 = (const float*)d_in[22];
    const float* Wh2  = (const float*)d_in[23];
    const float* bh2  = (const float*)d_in[24];
    const float* lhw2 = (const float*)d_in[25];
    const float* lhb2 = (const float*)d_in[26];
    const float* clsw = (const float*)d_in[27];
    const float* clsb = (const float*)d_in[28];

    float* ws   = (float*)d_ws;
    float* outp = (float*)d_out;

    build_A<<<1, 64, 0, stream>>>(ei, ew, ws + WS_A);
    pack_bot<<<32, 256, 0, stream>>>(lzw1, lrw1, (float4*)(ws + WS_LZR1), 2);
    pack_bot<<<16, 256, 0, stream>>>(lhw1, lhw1, (float4*)(ws + WS_LH1), 1);
    pack_bot<<<32, 256, 0, stream>>>(lzw2, lrw2, (float4*)(ws + WS_LZR2), 2);
    pack_bot<<<16, 256, 0, stream>>>(lhw2, lhw2, (float4*)(ws + WS_LH2), 1);
    make_weff2<<<48, 256, 0, stream>>>(Wz2, Wr2, Wh2, lzw2, lrw2, lhw2,
                                       (float4*)(ws + WS_WE2));
    make_vecs<<<5, 256, 0, stream>>>(Wz1, Wr1, Wh1, bz1, br1, bh1,
                                     lzw1, lrw1, lhw1, lzb1, lrb1, lhb1,
                                     bz2, br2, bh2, lzw2, lrw2, lhw2,
                                     lzb2, lrb2, lhb2, ws + WS_VEC);
    tgcn_main<<<64, NTHREADS, 0, stream>>>(x, ws, clsw, clsb, outp);
}

// Round 4
// 17393.060 us; speedup vs baseline: 1.4225x; 1.4225x over previous
//
#include <hip/hip_runtime.h>
#include <hip/hip_bf16.h>

// TGCN: B=64, T=500, N=21, HID=128.
// One block per batch element (64 x 256 threads), full T-loop in-kernel,
// H1/H2 in LDS. Round 4: G=4 row-groups x F=2 columns/thread (6 rows, 2 cols
// per thread, rows padded to 24). Per-step per-CU model: weight-L1 traffic
// = G*9216 cyc, LDS H-broadcasts = 80.6K/F cyc; G=4/F=2 balances both at
// ~40-46K cyc vs round1's 80K (LDS-bound) / round3's 101K (L1-bound).
// Per-element accumulation order IDENTICAL to passing rounds (c ascending,
// fma4 x..w, a-then-g per c in P4) — the 1.33e-6 threshold is thin; never
// reorder sums inside the recurrence.

#define NN 21
#define NROW 24            // padded rows (22,23 + 21 are zero rows)
#define HID 128
#define TSTEPS 500
#define EDGES 210
#define NTHREADS 256       // 4 waves
#define RPT 6              // rows per thread

// ws layout (float offsets)
#define WS_A     0        // NROW*NN floats (pad rows zeroed on load)
#define WS_VEC   1600     // 9*128
#define WS_LZR1  3200     // 32*256*4
#define WS_LH1   36000    // 32*128*4
#define WS_WE2   52400    // 32*384*4
#define WS_LZR2  101600   // 32*256*4
#define WS_LH2   134400   // 32*128*4

__device__ __forceinline__ float fma4(float4 a, float4 b, float acc) {
    acc = fmaf(a.x, b.x, acc);
    acc = fmaf(a.y, b.y, acc);
    acc = fmaf(a.z, b.z, acc);
    acc = fmaf(a.w, b.w, acc);
    return acc;
}

__device__ __forceinline__ float sigmoidf(float v) {
    return 1.0f / (1.0f + expf(-v));
}

// ---- Prologue: build normalized adjacency A (21x21) in fp64, store fp32 ----
__global__ void build_A(const int* __restrict__ ei, const float* __restrict__ ew,
                        float* __restrict__ Aout) {
    __shared__ double deg[NN];
    __shared__ double dinv[NN];
    __shared__ double Asm[NN * NN];
    int t = threadIdx.x;
    for (int k = t; k < NN * NN; k += blockDim.x) Asm[k] = 0.0;
    if (t < NN) deg[t] = 1.0;  // self loop weight 1
    __syncthreads();
    if (t == 0) {
        for (int e = 0; e < EDGES; e++) deg[ei[EDGES + e]] += (double)ew[e];
        for (int i = 0; i < NN; i++) dinv[i] = deg[i] > 0.0 ? 1.0 / sqrt(deg[i]) : 0.0;
        for (int e = 0; e < EDGES; e++) {
            int s = ei[e], d = ei[EDGES + e];
            Asm[d * NN + s] += dinv[s] * (double)ew[e] * dinv[d];
        }
        for (int i = 0; i < NN; i++) Asm[i * NN + i] += dinv[i] * dinv[i];
    }
    __syncthreads();
    for (int k = t; k < NROW * NN; k += blockDim.x)
        Aout[k] = (k < NN * NN) ? (float)Asm[k] : 0.0f;
}

// ---- Prologue: repack bottom halves of (256,128) concat weights ----
__global__ void pack_bot(const float* __restrict__ w0, const float* __restrict__ w1,
                         float4* __restrict__ out, int ngate) {
    int t = blockIdx.x * blockDim.x + threadIdx.x;
    int ncol = ngate * 128;
    int total = 32 * ncol;
    if (t >= total) return;
    int c = t / ncol, col = t - c * ncol;
    const float* src = (col < 128) ? w0 : w1;
    int f = col & 127;
    int k = 4 * c;
    float4 v;
    v.x = src[(128 + k + 0) * 128 + f];
    v.y = src[(128 + k + 1) * 128 + f];
    v.z = src[(128 + k + 2) * 128 + f];
    v.w = src[(128 + k + 3) * 128 + f];
    out[t] = v;
}

// ---- Prologue: Weff2_g = Wg_2 @ lgw_2_top, packed [c][g*128+f], fp64 accum ----
__global__ void make_weff2(const float* __restrict__ Wz2, const float* __restrict__ Wr2,
                           const float* __restrict__ Wh2,
                           const float* __restrict__ lzw2, const float* __restrict__ lrw2,
                           const float* __restrict__ lhw2,
                           float4* __restrict__ out) {
    int t = blockIdx.x * blockDim.x + threadIdx.x;  // [0, 32*384)
    if (t >= 32 * 384) return;
    int c = t / 384, col = t - c * 384;
    int g = col >> 7, f = col & 127;
    const float* W = (g == 0) ? Wz2 : (g == 1) ? Wr2 : Wh2;
    const float* L = (g == 0) ? lzw2 : (g == 1) ? lrw2 : lhw2;
    double a0 = 0, a1 = 0, a2 = 0, a3 = 0;
    for (int m = 0; m < 128; m++) {
        double lm = (double)L[m * 128 + f];
        a0 += (double)W[(4 * c + 0) * 128 + m] * lm;
        a1 += (double)W[(4 * c + 1) * 128 + m] * lm;
        a2 += (double)W[(4 * c + 2) * 128 + m] * lm;
        a3 += (double)W[(4 * c + 3) * 128 + m] * lm;
    }
    out[t] = make_float4((float)a0, (float)a1, (float)a2, (float)a3);
}

// ---- Prologue: layer-1 effective row vectors + all bias consts (fp64) ----
__global__ void make_vecs(const float* __restrict__ Wz1, const float* __restrict__ Wr1,
                          const float* __restrict__ Wh1,
                          const float* __restrict__ bz1, const float* __restrict__ br1,
                          const float* __restrict__ bh1,
                          const float* __restrict__ lzw1, const float* __restrict__ lrw1,
                          const float* __restrict__ lhw1,
                          const float* __restrict__ lzb1, const float* __restrict__ lrb1,
                          const float* __restrict__ lhb1,
                          const float* __restrict__ bz2, const float* __restrict__ br2,
                          const float* __restrict__ bh2,
                          const float* __restrict__ lzw2, const float* __restrict__ lrw2,
                          const float* __restrict__ lhw2,
                          const float* __restrict__ lzb2, const float* __restrict__ lrb2,
                          const float* __restrict__ lhb2,
                          float* __restrict__ out) {
    int t = blockIdx.x * blockDim.x + threadIdx.x;
    if (t >= 9 * 128) return;
    int v = t >> 7, f = t & 127;
    double acc = 0.0;
    if (v < 3) {
        const float* W = (v == 0) ? Wz1 : (v == 1) ? Wr1 : Wh1;   // (1,128)
        const float* L = (v == 0) ? lzw1 : (v == 1) ? lrw1 : lhw1;
        for (int m = 0; m < 128; m++) acc += (double)W[m] * (double)L[m * 128 + f];
    } else if (v < 6) {
        int g = v - 3;
        const float* bb = (g == 0) ? bz1 : (g == 1) ? br1 : bh1;
        const float* L  = (g == 0) ? lzw1 : (g == 1) ? lrw1 : lhw1;
        const float* lb = (g == 0) ? lzb1 : (g == 1) ? lrb1 : lhb1;
        for (int m = 0; m < 128; m++) acc += (double)bb[m] * (double)L[m * 128 + f];
        acc += (double)lb[f];
    } else {
        int g = v - 6;
        const float* bb = (g == 0) ? bz2 : (g == 1) ? br2 : bh2;
        const float* L  = (g == 0) ? lzw2 : (g == 1) ? lrw2 : lhw2;
        const float* lb = (g == 0) ? lzb2 : (g == 1) ? lrb2 : lhb2;
        for (int m = 0; m < 128; m++) acc += (double)bb[m] * (double)L[m * 128 + f];
        acc += (double)lb[f];
    }
    out[t] = (float)acc;
}

// ---- Main: one block per batch element, T=500 steps in-kernel ----
__global__ __launch_bounds__(NTHREADS, 1) void tgcn_main(
    const float* __restrict__ x,       // (64,500,21)
    const float* __restrict__ ws,
    const float* __restrict__ cls_w,   // (128,1)
    const float* __restrict__ cls_b,   // (1,)
    float* __restrict__ out)           // (64,)
{
    const int b  = blockIdx.x;
    const int t  = threadIdx.x;
    const int f0 = t & 63;
    const int f1 = f0 + 64;
    const int g  = __builtin_amdgcn_readfirstlane(t >> 6);  // wave-uniform 0..3
    const int iA = g * RPT;                                 // first owned row
    const int nreal = (iA + RPT <= NN) ? RPT : (NN - iA);   // real rows (wave-uniform)

    __shared__ __align__(16) float sH1[NROW * HID];
    __shared__ __align__(16) float sH2[NROW * HID];
    __shared__ __align__(16) float sHR[NROW * HID];
    __shared__ __align__(16) float sAH[NROW * HID];
    __shared__ float sA[NROW * NN];    // pad rows zero
    __shared__ float sax[2][NROW];
    __shared__ double sred[4][HID];

    const float*  vecs = ws + WS_VEC;
    const float4* Lzr1 = (const float4*)(ws + WS_LZR1);
    const float4* Lh1  = (const float4*)(ws + WS_LH1);
    const float4* We2  = (const float4*)(ws + WS_WE2);
    const float4* Lzr2 = (const float4*)(ws + WS_LZR2);
    const float4* Lh2  = (const float4*)(ws + WS_LH2);

    const float4* H1v = (const float4*)sH1;   // row stride 32 float4
    const float4* H2v = (const float4*)sH2;
    const float4* HRv = (const float4*)sHR;
    const float4* AHv = (const float4*)sAH;

    for (int k = t; k < NROW * HID; k += NTHREADS) { sH1[k] = 0.0f; sH2[k] = 0.0f; }
    for (int k = t; k < NROW * NN; k += NTHREADS) sA[k] = ws[WS_A + k];

    // per-column constants for both owned columns
    const float wz1a = vecs[f0],        wz1b = vecs[f1];
    const float wr1a = vecs[128 + f0],  wr1b = vecs[128 + f1];
    const float wh1a = vecs[256 + f0],  wh1b = vecs[256 + f1];
    const float cz1a = vecs[384 + f0],  cz1b = vecs[384 + f1];
    const float cr1a = vecs[512 + f0],  cr1b = vecs[512 + f1];
    const float ch1a = vecs[640 + f0],  ch1b = vecs[640 + f1];
    const float cz2a = vecs[768 + f0],  cz2b = vecs[768 + f1];
    const float cr2a = vecs[896 + f0],  cr2b = vecs[896 + f1];
    const float ch2a = vecs[1024 + f0], ch2b = vecs[1024 + f1];

    __syncthreads();

    const float* xb = x + (size_t)b * (TSTEPS * NN);
    if (t < NROW) {  // sax for step 0 (pad rows -> 0 since A pad rows are zero)
        float a = 0.0f;
        for (int j = 0; j < NN; j++) a = fmaf(sA[t * NN + j], xb[j], a);
        sax[0][t] = a;
    }
    __syncthreads();

    double oacc0 = 0.0, oacc1 = 0.0;

    for (int step = 0; step < TSTEPS; step++) {
        const int pb = step & 1;
        float ax[RPT];
        #pragma unroll
        for (int r = 0; r < RPT; r++) ax[r] = sax[pb][iA + r];

        // ---------- P1: layer-1 z,r gates ----------
        float az0[RPT], az1[RPT], ar0[RPT], ar1[RPT];
        #pragma unroll
        for (int r = 0; r < RPT; r++) {
            az0[r] = fmaf(ax[r], wz1a, cz1a);
            az1[r] = fmaf(ax[r], wz1b, cz1b);
            ar0[r] = fmaf(ax[r], wr1a, cr1a);
            ar1[r] = fmaf(ax[r], wr1b, cr1b);
        }
        #pragma unroll 2
        for (int c = 0; c < 32; ++c) {
            const float4 wz0 = Lzr1[c * 256 + f0];
            const float4 wz1 = Lzr1[c * 256 + f1];
            const float4 wr0 = Lzr1[c * 256 + 128 + f0];
            const float4 wr1 = Lzr1[c * 256 + 128 + f1];
            #pragma unroll
            for (int r = 0; r < RPT; r++) {
                const float4 h = H1v[(iA + r) * 32 + c];
                az0[r] = fma4(h, wz0, az0[r]);
                az1[r] = fma4(h, wz1, az1[r]);
                ar0[r] = fma4(h, wr0, ar0[r]);
                ar1[r] = fma4(h, wr1, ar1[r]);
            }
        }
        float z0[RPT], z1[RPT], r0g[RPT], r1g[RPT], h1c0[RPT], h1c1[RPT];
        #pragma unroll
        for (int r = 0; r < RPT; r++) {
            z0[r]  = sigmoidf(az0[r]);
            z1[r]  = sigmoidf(az1[r]);
            r0g[r] = sigmoidf(ar0[r]);
            r1g[r] = sigmoidf(ar1[r]);
            h1c0[r] = sH1[(iA + r) * HID + f0];
            h1c1[r] = sH1[(iA + r) * HID + f1];
            sHR[(iA + r) * HID + f0] = h1c0[r] * r0g[r];
            sHR[(iA + r) * HID + f1] = h1c1[r] * r1g[r];
        }
        __syncthreads();

        // ---------- P2: layer-1 h gate + H1 update ----------
        float ah0[RPT], ah1[RPT];
        #pragma unroll
        for (int r = 0; r < RPT; r++) {
            ah0[r] = fmaf(ax[r], wh1a, ch1a);
            ah1[r] = fmaf(ax[r], wh1b, ch1b);
        }
        #pragma unroll 2
        for (int c = 0; c < 32; ++c) {
            const float4 wh0 = Lh1[c * 128 + f0];
            const float4 wh1 = Lh1[c * 128 + f1];
            #pragma unroll
            for (int r = 0; r < RPT; r++) {
                const float4 q = HRv[(iA + r) * 32 + c];
                ah0[r] = fma4(q, wh0, ah0[r]);
                ah1[r] = fma4(q, wh1, ah1[r]);
            }
        }
        #pragma unroll
        for (int r = 0; r < RPT; r++) {
            const float n0 = fmaf(z0[r], h1c0[r], (1.0f - z0[r]) * tanhf(ah0[r]));
            const float n1 = fmaf(z1[r], h1c1[r], (1.0f - z1[r]) * tanhf(ah1[r]));
            sH1[(iA + r) * HID + f0] = n0;
            sH1[(iA + r) * HID + f1] = n1;
        }
        __syncthreads();

        // ---------- P3: AH1 = A @ H1 ----------
        {
            float aa0[RPT], aa1[RPT];
            #pragma unroll
            for (int r = 0; r < RPT; r++) { aa0[r] = 0.0f; aa1[r] = 0.0f; }
            #pragma unroll 3
            for (int j = 0; j < NN; j++) {
                const float hj0 = sH1[j * HID + f0];
                const float hj1 = sH1[j * HID + f1];
                #pragma unroll
                for (int r = 0; r < RPT; r++) {
                    const float arj = sA[(iA + r) * NN + j];
                    aa0[r] = fmaf(arj, hj0, aa0[r]);
                    aa1[r] = fmaf(arj, hj1, aa1[r]);
                }
            }
            #pragma unroll
            for (int r = 0; r < RPT; r++) {
                sAH[(iA + r) * HID + f0] = aa0[r];
                sAH[(iA + r) * HID + f1] = aa1[r];
            }
        }
        __syncthreads();

        // ---------- P4: layer-2 gcn (all gates) + z,r gates ----------
        float pz0[RPT], pz1[RPT], pr0[RPT], pr1[RPT], ph0[RPT], ph1[RPT];
        #pragma unroll
        for (int r = 0; r < RPT; r++) {
            pz0[r] = cz2a; pz1[r] = cz2b;
            pr0[r] = cr2a; pr1[r] = cr2b;
            ph0[r] = ch2a; ph1[r] = ch2b;
        }
        for (int c = 0; c < 32; ++c) {
            const float4 wz0 = We2[c * 384 + f0];
            const float4 wz1 = We2[c * 384 + f1];
            const float4 wr0 = We2[c * 384 + 128 + f0];
            const float4 wr1 = We2[c * 384 + 128 + f1];
            const float4 wh0 = We2[c * 384 + 256 + f0];
            const float4 wh1 = We2[c * 384 + 256 + f1];
            const float4 lz0 = Lzr2[c * 256 + f0];
            const float4 lz1 = Lzr2[c * 256 + f1];
            const float4 lr0 = Lzr2[c * 256 + 128 + f0];
            const float4 lr1 = Lzr2[c * 256 + 128 + f1];
            #pragma unroll
            for (int r = 0; r < RPT; r++) {
                const float4 a = AHv[(iA + r) * 32 + c];
                const float4 q = H2v[(iA + r) * 32 + c];
                // per-element order: a-chunk then g-chunk per c (matches round 1)
                pz0[r] = fma4(a, wz0, pz0[r]); pz0[r] = fma4(q, lz0, pz0[r]);
                pz1[r] = fma4(a, wz1, pz1[r]); pz1[r] = fma4(q, lz1, pz1[r]);
                pr0[r] = fma4(a, wr0, pr0[r]); pr0[r] = fma4(q, lr0, pr0[r]);
                pr1[r] = fma4(a, wr1, pr1[r]); pr1[r] = fma4(q, lr1, pr1[r]);
                ph0[r] = fma4(a, wh0, ph0[r]);
                ph1[r] = fma4(a, wh1, ph1[r]);
            }
        }
        float z20[RPT], z21[RPT], h2c0[RPT], h2c1[RPT];
        #pragma unroll
        for (int r = 0; r < RPT; r++) {
            z20[r] = sigmoidf(pz0[r]);
            z21[r] = sigmoidf(pz1[r]);
            const float r20 = sigmoidf(pr0[r]);
            const float r21 = sigmoidf(pr1[r]);
            h2c0[r] = sH2[(iA + r) * HID + f0];
            h2c1[r] = sH2[(iA + r) * HID + f1];
            sHR[(iA + r) * HID + f0] = h2c0[r] * r20;
            sHR[(iA + r) * HID + f1] = h2c1[r] * r21;
        }
        __syncthreads();

        // ---------- P5: layer-2 h gate + H2 update + output accum ----------
        #pragma unroll 2
        for (int c = 0; c < 32; ++c) {
            const float4 lh0 = Lh2[c * 128 + f0];
            const float4 lh1 = Lh2[c * 128 + f1];
            #pragma unroll
            for (int r = 0; r < RPT; r++) {
                const float4 q = HRv[(iA + r) * 32 + c];
                ph0[r] = fma4(q, lh0, ph0[r]);
                ph1[r] = fma4(q, lh1, ph1[r]);
            }
        }
        #pragma unroll
        for (int r = 0; r < RPT; r++) {
            const float m0 = fmaf(z20[r], h2c0[r], (1.0f - z20[r]) * tanhf(ph0[r]));
            const float m1 = fmaf(z21[r], h2c1[r], (1.0f - z21[r]) * tanhf(ph1[r]));
            sH2[(iA + r) * HID + f0] = m0;
            sH2[(iA + r) * HID + f1] = m1;
            if (r < nreal) {            // wave-uniform: exclude pad rows
                oacc0 += (double)m0;
                oacc1 += (double)m1;
            }
        }

        // prefetch next step's ax (threads 0..23; pad rows -> 0)
        if (step + 1 < TSTEPS && t < NROW) {
            const float* xt = xb + (step + 1) * NN;
            float a = 0.0f;
            for (int j = 0; j < NN; j++) a = fmaf(sA[t * NN + j], xt[j], a);
            sax[(step + 1) & 1][t] = a;
        }
        __syncthreads();
    }

    // ---------- Epilogue: mean over (T, nodes), dot with cls_w ----------
    sred[g][f0] = oacc0;
    sred[g][f1] = oacc1;
    __syncthreads();
    if (t < HID) {
        double s = 0.0;
        for (int gg = 0; gg < 4; gg++) s += sred[gg][t];
        sred[0][t] = (s / (double)(TSTEPS * NN)) * (double)cls_w[t];
    }
    __syncthreads();
    if (t < 64) {
        double v = ((double*)sred)[t] + ((double*)sred)[t + 64];
        for (int off = 32; off; off >>= 1) v += __shfl_down(v, off, 64);
        if (t == 0) out[b] = (float)(v + (double)cls_b[0]);
    }
}

extern "C" void kernel_launch(void* const* d_in, const int* in_sizes, int n_in,
                              void* d_out, int out_size, void* d_ws, size_t ws_size,
                              hipStream_t stream) {
    const float* x    = (const float*)d_in[0];
    const int*   ei   = (const int*)  d_in[1];
    const float* ew   = (const float*)d_in[2];
    const float* Wz1  = (const float*)d_in[3];
    const float* bz1  = (const float*)d_in[4];
    const float* lzw1 = (const float*)d_in[5];
    const float* lzb1 = (const float*)d_in[6];
    const float* Wr1  = (const float*)d_in[7];
    const float* br1  = (const float*)d_in[8];
    const float* lrw1 = (const float*)d_in[9];
    const float* lrb1 = (const float*)d_in[10];
    const float* Wh1  = (const float*)d_in[11];
    const float* bh1  = (const float*)d_in[12];
    const float* lhw1 = (const float*)d_in[13];
    const float* lhb1 = (const float*)d_in[14];
    const float* Wz2  = (const float*)d_in[15];
    const float* bz2  = (const float*)d_in[16];
    const float* lzw2 = (const float*)d_in[17];
    const float* lzb2 = (const float*)d_in[18];
    const float* Wr2  = (const float*)d_in[19];
    const float* br2  = (const float*)d_in[20];
    const float* lrw2 = (const float*)d_in[21];
    const float* lrb2 = (const float*)d_in[22];
    const float* Wh2  = (const float*)d_in[23];
    const float* bh2  = (const float*)d_in[24];
    const float* lhw2 = (const float*)d_in[25];
    const float* lhb2 = (const float*)d_in[26];
    const float* clsw = (const float*)d_in[27];
    const float* clsb = (const float*)d_in[28];

    float* ws   = (float*)d_ws;
    float* outp = (float*)d_out;

    build_A<<<1, 64, 0, stream>>>(ei, ew, ws + WS_A);
    pack_bot<<<32, 256, 0, stream>>>(lzw1, lrw1, (float4*)(ws + WS_LZR1), 2);
    pack_bot<<<16, 256, 0, stream>>>(lhw1, lhw1, (float4*)(ws + WS_LH1), 1);
    pack_bot<<<32, 256, 0, stream>>>(lzw2, lrw2, (float4*)(ws + WS_LZR2), 2);
    pack_bot<<<16, 256, 0, stream>>>(lhw2, lhw2, (float4*)(ws + WS_LH2), 1);
    make_weff2<<<48, 256, 0, stream>>>(Wz2, Wr2, Wh2, lzw2, lrw2, lhw2,
                                       (float4*)(ws + WS_WE2));
    make_vecs<<<5, 256, 0, stream>>>(Wz1, Wr1, Wh1, bz1, br1, bh1,
                                     lzw1, lrw1, lhw1, lzb1, lrb1, lhb1,
                                     bz2, br2, bh2, lzw2, lrw2, lhw2,
                                     lzb2, lrb2, lhb2, ws + WS_VEC);
    tgcn_main<<<64, NTHREADS, 0, stream>>>(x, ws, clsw, clsb, outp);
}